// Round 7
// baseline (383.063 us; speedup 1.0000x reference)
//
#include <hip/hip_runtime.h>
#include <hip/hip_bf16.h>
#include <stdint.h>

#define B_ 4
#define N_ 2048
#define D_ 1024
#define K_ 16
#define MROWS (B_*N_)      // 8192
#define NC_ 32
#define CLEN_ (N_/NC_)     // 64

typedef unsigned short u16;
typedef __attribute__((ext_vector_type(8))) short bf16x8;
typedef __attribute__((ext_vector_type(4))) float f32x4;

__device__ __forceinline__ u16 f2bf(float f) {
  uint32_t u = __float_as_uint(f);
  u = u + 0x7fffu + ((u >> 16) & 1u);
  return (u16)(u >> 16);
}

// ---------------- cast fp32 -> bf16 (vectorized) ----------------
__global__ __launch_bounds__(256) void cast_kernel(const float* __restrict__ in,
                                                   u16* __restrict__ out, int n) {
  int i = (blockIdx.x * 256 + threadIdx.x) * 4;
  if (i >= n) return;
  float4 v = *(const float4*)(in + i);
  ushort4 o;
  o.x = f2bf(v.x); o.y = f2bf(v.y); o.z = f2bf(v.z); o.w = f2bf(v.w);
  *(ushort4*)(out + i) = o;
}

#define GL_LDS(gp, lp) \
  __builtin_amdgcn_global_load_lds( \
      (const __attribute__((address_space(1))) void*)(gp), \
      (__attribute__((address_space(3))) void*)(lp), 16, 0, 0)

#define WAITVM(n)  asm volatile("s_waitcnt vmcnt(" #n ")" ::: "memory")
#define SCHEDB()   __builtin_amdgcn_sched_barrier(0)

// ---------------- counted-vmcnt ring GEMM (R4 structure, best measured) ----
// ABL: 0 = production, 1 = no-stage (skeleton), 2 = no-mfma (staging only)
template<int ABL, bool FUSED>
__device__ __forceinline__ void ring_body(const u16* __restrict__ A,
                                          const u16* __restrict__ W0,
                                          const u16* __restrict__ W1,
                                          float* __restrict__ C0,
                                          float* __restrict__ C1) {
  __shared__ __align__(16) u16 lds[3 * 24576];   // 147456 B

  const int tid = threadIdx.x;
  const int w = tid >> 6, l = tid & 63;
  const int wr = w >> 1, wc = w & 1;

  const int nwg = FUSED ? 512 : 256;
  const int NBN = FUSED ? 16 : 8;
  const int orig = blockIdx.x;
  const int wg = (orig & 7) * (nwg >> 3) + (orig >> 3);
  const int bm = wg / NBN;
  const int bn = wg % NBN;

  const u16* W;
  float* C;
  bool fgate = false;
  int ncol0;
  if (FUSED && bn >= 8) {
    W = W1; C = C1; fgate = true; ncol0 = (bn - 8) * 128;
  } else {
    W = W0; C = C0; ncol0 = bn * 128;
  }

  const int sw = ((l & 7) ^ ((l >> 3) & 7)) * 8;
  const u16* aSrc = A + (size_t)(bm * 256 + w * 8 + (l >> 3)) * 1024 + sw;
  const u16* bSrc = W + (size_t)(ncol0 + w * 8 + (l >> 3)) * 1024 + sw;

#define STAGE_T(t, slot) do { \
    const int _sb = (slot) * 49152 + w * 1024; \
    _Pragma("unroll") \
    for (int j = 0; j < 4; ++j) \
      GL_LDS(aSrc + (size_t)j * 65536 + (t) * 64, (char*)lds + _sb + j * 8192); \
    _Pragma("unroll") \
    for (int j = 0; j < 2; ++j) \
      GL_LDS(bSrc + (size_t)j * 65536 + (t) * 64, (char*)lds + _sb + 32768 + j * 8192); \
  } while (0)

  const int sxe = (l & 7) << 3;
  const int klo = (l >> 4) * 8;
  const int aR0 = (wr * 64 + (l & 15)) * 64;
  const int bR0 = (wc * 64 + (l & 15)) * 64 + 16384;

  f32x4 acc[4][4] = {};

#define COMPUTE(slot) do { \
    const u16* S = lds + (slot) * 24576; \
    bf16x8 b0[4], a0[4], b1[4], a1[4]; \
    _Pragma("unroll") \
    for (int n = 0; n < 4; ++n) b0[n] = *(const bf16x8*)&S[bR0 + n * 1024 + (klo ^ sxe)]; \
    _Pragma("unroll") \
    for (int m = 0; m < 4; ++m) a0[m] = *(const bf16x8*)&S[aR0 + m * 1024 + (klo ^ sxe)]; \
    _Pragma("unroll") \
    for (int n = 0; n < 4; ++n) b1[n] = *(const bf16x8*)&S[bR0 + n * 1024 + ((klo + 32) ^ sxe)]; \
    _Pragma("unroll") \
    for (int m = 0; m < 4; ++m) a1[m] = *(const bf16x8*)&S[aR0 + m * 1024 + ((klo + 32) ^ sxe)]; \
    asm volatile("s_waitcnt lgkmcnt(8)" ::: "memory"); \
    SCHEDB(); \
    __builtin_amdgcn_s_setprio(1); \
    _Pragma("unroll") \
    for (int m = 0; m < 4; ++m) \
      _Pragma("unroll") \
      for (int n = 0; n < 4; ++n) \
        acc[m][n] = __builtin_amdgcn_mfma_f32_16x16x32_bf16(a0[m], b0[n], acc[m][n], 0, 0, 0); \
    __builtin_amdgcn_s_setprio(0); \
    asm volatile("s_waitcnt lgkmcnt(0)" ::: "memory"); \
    SCHEDB(); \
    __builtin_amdgcn_s_setprio(1); \
    _Pragma("unroll") \
    for (int m = 0; m < 4; ++m) \
      _Pragma("unroll") \
      for (int n = 0; n < 4; ++n) \
        acc[m][n] = __builtin_amdgcn_mfma_f32_16x16x32_bf16(a1[m], b1[n], acc[m][n], 0, 0, 0); \
    __builtin_amdgcn_s_setprio(0); \
  } while (0)

  STAGE_T(0, 0);
  STAGE_T(1, 1);
  WAITVM(6);
  __builtin_amdgcn_s_barrier();
  SCHEDB();

#pragma unroll
  for (int t = 0; t < 16; ++t) {
    if (ABL != 1) { if (t + 2 < 16) STAGE_T(t + 2, (t + 2) % 3); }
    if (ABL != 2) { COMPUTE(t % 3); }
    if (t < 15) {
      if (t == 14) WAITVM(0);
      else         WAITVM(6);
      __builtin_amdgcn_s_barrier();
      SCHEDB();
    }
  }

  const int orow0 = bm * 256 + wr * 64 + (l >> 4) * 4;
  const int ocol0 = ncol0 + wc * 64 + (l & 15);
#pragma unroll
  for (int m = 0; m < 4; ++m) {
#pragma unroll
    for (int n = 0; n < 4; ++n) {
#pragma unroll
      for (int r = 0; r < 4; ++r) {
        int row = orow0 + m * 16 + r;
        int col = ocol0 + n * 16;
        float v = acc[m][n][r];
        if (FUSED && fgate && ABL == 0) {
          float ls = (v >= 0.0f) ? -log1pf(expf(-v)) : (v - log1pf(expf(v)));
          v = expf(ls * (1.0f / 16.0f));
        }
        C[(size_t)row * 1024 + col] = v;
      }
    }
  }
#undef STAGE_T
#undef COMPUTE
}

__global__ __launch_bounds__(512, 1) void ring_fused_prod(const u16* A, const u16* W0, const u16* W1,
                                                          float* C0, float* C1) {
  ring_body<0, true>(A, W0, W1, C0, C1);
}
__global__ __launch_bounds__(512, 1) void ring_abl_nostage(const u16* A, const u16* W0, const u16* W1,
                                                           float* C0, float* C1) {
  ring_body<1, true>(A, W0, W1, C0, C1);
}
__global__ __launch_bounds__(512, 1) void ring_abl_nomfma(const u16* A, const u16* W0, const u16* W1,
                                                          float* C0, float* C1) {
  ring_body<2, true>(A, W0, W1, C0, C1);
}

// ---------------- R1-style simple GEMM (best measured o-proj) ----------------
__device__ __forceinline__ void bt_body(const u16* __restrict__ A,
                                        const u16* __restrict__ W,
                                        float* __restrict__ C) {
  __shared__ u16 As[128 * 32];
  __shared__ u16 Bs[128 * 32];
  const int tid = threadIdx.x;
  const int w = tid >> 6, l = tid & 63;
  const int bm = blockIdx.x / 8, bn = blockIdx.x % 8;
  const int wm = (w >> 1) * 64, wn = (w & 1) * 64;
  const int lr = l & 15, lk = (l >> 4) * 8;

  f32x4 acc[4][4] = {};

  for (int kt = 0; kt < 1024; kt += 32) {
#pragma unroll
    for (int j = 0; j < 2; ++j) {
      int ofs = w * 1024 + j * 4096;
      int gofs = ofs + l * 16;
      int row = gofs >> 6;
      int ke = (gofs & 63) >> 1;
      const u16* ga = A + (size_t)(bm * 128 + row) * 1024 + kt + ke;
      const u16* gb = W + (size_t)(bn * 128 + row) * 1024 + kt + ke;
      GL_LDS(ga, (char*)As + ofs);
      GL_LDS(gb, (char*)Bs + ofs);
    }
    __syncthreads();
    bf16x8 af[4], bfr[4];
#pragma unroll
    for (int i2 = 0; i2 < 4; ++i2) {
      af[i2]  = *(const bf16x8*)&As[(wm + i2 * 16 + lr) * 32 + lk];
      bfr[i2] = *(const bf16x8*)&Bs[(wn + i2 * 16 + lr) * 32 + lk];
    }
#pragma unroll
    for (int i2 = 0; i2 < 4; ++i2)
#pragma unroll
      for (int j2 = 0; j2 < 4; ++j2)
        acc[i2][j2] = __builtin_amdgcn_mfma_f32_16x16x32_bf16(af[i2], bfr[j2], acc[i2][j2], 0, 0, 0);
    __syncthreads();
  }

  const int orow0 = bm * 128 + wm + (l >> 4) * 4;
  const int ocol0 = bn * 128 + wn + (l & 15);
#pragma unroll
  for (int i2 = 0; i2 < 4; ++i2)
#pragma unroll
    for (int j2 = 0; j2 < 4; ++j2)
#pragma unroll
      for (int r = 0; r < 4; ++r)
        C[(size_t)(orow0 + i2 * 16 + r) * 1024 + ocol0 + j2 * 16] = acc[i2][j2][r];
}

__global__ __launch_bounds__(256) void gemm_bt_out(const u16* A, const u16* W, float* C) {
  bt_body(A, W, C);
}
__global__ __launch_bounds__(256) void gemm_bt_ws(const u16* A, const u16* W, float* C) {
  bt_body(A, W, C);
}

// ---------------- e/s projections ----------------
__global__ __launch_bounds__(256) void es_proj(const float* __restrict__ x,
                                               const float* __restrict__ We,
                                               const float* __restrict__ Ws,
                                               float* __restrict__ e,
                                               float* __restrict__ s) {
  int row = blockIdx.x * 4 + (threadIdx.x >> 6);
  int l = threadIdx.x & 63;
  const float* xr = x + (size_t)row * D_;
  float4 xv[4];
#pragma unroll
  for (int j = 0; j < 4; ++j) xv[j] = *(const float4*)(xr + j * 256 + l * 4);
  float pe[K_], ps[K_];
#pragma unroll
  for (int k = 0; k < K_; ++k) {
    float ae = 0.f, as_ = 0.f;
#pragma unroll
    for (int j = 0; j < 4; ++j) {
      float4 wv = *(const float4*)(We + (size_t)k * D_ + j * 256 + l * 4);
      float4 sv = *(const float4*)(Ws + (size_t)k * D_ + j * 256 + l * 4);
      ae  += xv[j].x * wv.x + xv[j].y * wv.y + xv[j].z * wv.z + xv[j].w * wv.w;
      as_ += xv[j].x * sv.x + xv[j].y * sv.y + xv[j].z * sv.z + xv[j].w * sv.w;
    }
    pe[k] = ae; ps[k] = as_;
  }
#pragma unroll
  for (int k = 0; k < K_; ++k) {
    float ae = pe[k], as_ = ps[k];
    for (int off = 32; off > 0; off >>= 1) {
      ae  += __shfl_down(ae, off);
      as_ += __shfl_down(as_, off);
    }
    if (l == 0) {
      e[(size_t)row * K_ + k] = ae;
      s[(size_t)row * K_ + k] = as_;
    }
  }
}

// ---------------- scan pass1 ----------------
__global__ __launch_bounds__(256) void scan_pass1(const float* __restrict__ ibuf,
                                                  const float* __restrict__ fbuf,
                                                  const float* __restrict__ ebuf,
                                                  float* __restrict__ Asc,
                                                  float* __restrict__ Psc) {
  int bid = blockIdx.x;
  int dq = bid & 3, c = (bid >> 2) & (NC_ - 1), b = bid >> 7;
  int d = dq * 256 + threadIdx.x;
  int t0 = c * CLEN_;
  float m[K_];
#pragma unroll
  for (int k = 0; k < K_; ++k) m[k] = 0.f;
  float p = 1.0f;
  const float* ip = ibuf + ((size_t)b * N_ + t0) * D_ + d;
  const float* fp = fbuf + ((size_t)b * N_ + t0) * D_ + d;
  const float* ep = ebuf + ((size_t)b * N_ + t0) * K_;
  for (int t = 0; t < CLEN_; ++t) {
    float it = ip[(size_t)t * D_];
    float ft = fp[(size_t)t * D_];
    p *= ft;
#pragma unroll
    for (int k = 0; k < K_; ++k) m[k] = ft * m[k] + ep[t * K_ + k] * it;
  }
  float* ap = Asc + (((size_t)b * NC_ + c) * K_) * D_ + d;
#pragma unroll
  for (int k = 0; k < K_; ++k) ap[(size_t)k * D_] = m[k];
  Psc[((size_t)b * NC_ + c) * D_ + d] = p;
}

// ---------------- scan pass2 ----------------
__global__ __launch_bounds__(256) void scan_pass2(const float* __restrict__ Asc,
                                                  const float* __restrict__ Psc,
                                                  float* __restrict__ Ssc) {
  int idx = blockIdx.x * 256 + threadIdx.x;
  int d = idx & (D_ - 1);
  int k = (idx >> 10) & (K_ - 1);
  int b = idx >> 14;
  float M = 0.f;
  for (int c = 0; c < NC_; ++c) {
    size_t base = (((size_t)b * NC_ + c) * K_ + k) * D_ + d;
    float a = Asc[base];
    float pp = Psc[((size_t)b * NC_ + c) * D_ + d];
    Ssc[base] = M;
    M = pp * M + a;
  }
}

// ---------------- scan pass3 ----------------
__global__ __launch_bounds__(256) void scan_pass3(float* __restrict__ ibuf,
                                                  const float* __restrict__ fbuf,
                                                  const float* __restrict__ ebuf,
                                                  const float* __restrict__ sbuf,
                                                  const float* __restrict__ Ssc) {
  int bid = blockIdx.x;
  int dq = bid & 3, c = (bid >> 2) & (NC_ - 1), b = bid >> 7;
  int d = dq * 256 + threadIdx.x;
  int t0 = c * CLEN_;
  float m[K_];
  const float* sp0 = Ssc + (((size_t)b * NC_ + c) * K_) * D_ + d;
#pragma unroll
  for (int k = 0; k < K_; ++k) m[k] = sp0[(size_t)k * D_];
  float* ip = ibuf + ((size_t)b * N_ + t0) * D_ + d;
  const float* fp = fbuf + ((size_t)b * N_ + t0) * D_ + d;
  const float* ep = ebuf + ((size_t)b * N_ + t0) * K_;
  const float* zp = sbuf + ((size_t)b * N_ + t0) * K_;
  for (int t = 0; t < CLEN_; ++t) {
    float it = ip[(size_t)t * D_];
    float ft = fp[(size_t)t * D_];
    float y = 0.f;
#pragma unroll
    for (int k = 0; k < K_; ++k) {
      m[k] = ft * m[k] + ep[t * K_ + k] * it;
      y += zp[t * K_ + k] * m[k];
    }
    ip[(size_t)t * D_] = y;
  }
}

// ---------------- LayerNorm -> bf16 ----------------
__global__ __launch_bounds__(256) void ln_kernel(const float* __restrict__ y,
                                                 const float* __restrict__ gamma,
                                                 const float* __restrict__ beta,
                                                 u16* __restrict__ yn) {
  int row = blockIdx.x * 4 + (threadIdx.x >> 6);
  int l = threadIdx.x & 63;
  const float* yr = y + (size_t)row * D_;
  float4 v[4];
  float sum = 0.f;
#pragma unroll
  for (int j = 0; j < 4; ++j) {
    v[j] = *(const float4*)(yr + j * 256 + l * 4);
    sum += v[j].x + v[j].y + v[j].z + v[j].w;
  }
  for (int off = 32; off > 0; off >>= 1) sum += __shfl_xor(sum, off);
  float mu = sum * (1.0f / D_);
  float vs = 0.f;
#pragma unroll
  for (int j = 0; j < 4; ++j) {
    float dx = v[j].x - mu; vs += dx * dx;
    dx = v[j].y - mu; vs += dx * dx;
    dx = v[j].z - mu; vs += dx * dx;
    dx = v[j].w - mu; vs += dx * dx;
  }
  for (int off = 32; off > 0; off >>= 1) vs += __shfl_xor(vs, off);
  float rstd = rsqrtf(vs * (1.0f / D_) + 1e-5f);
#pragma unroll
  for (int j = 0; j < 4; ++j) {
    int col = j * 256 + l * 4;
    float4 g = *(const float4*)(gamma + col);
    float4 bt = *(const float4*)(beta + col);
    ushort4 o;
    o.x = f2bf((v[j].x - mu) * rstd * g.x + bt.x);
    o.y = f2bf((v[j].y - mu) * rstd * g.y + bt.y);
    o.z = f2bf((v[j].z - mu) * rstd * g.z + bt.z);
    o.w = f2bf((v[j].w - mu) * rstd * g.w + bt.w);
    *(ushort4*)(yn + (size_t)row * D_ + col) = o;
  }
}

extern "C" void kernel_launch(void* const* d_in, const int* in_sizes, int n_in,
                              void* d_out, int out_size, void* d_ws, size_t ws_size,
                              hipStream_t stream) {
  const float* x     = (const float*)d_in[0];
  const float* Wi    = (const float*)d_in[1];
  const float* We    = (const float*)d_in[2];
  const float* Wf    = (const float*)d_in[3];
  const float* Ws    = (const float*)d_in[4];
  const float* gamma = (const float*)d_in[5];
  const float* beta  = (const float*)d_in[6];
  const float* Wo    = (const float*)d_in[7];
  float* out = (float*)d_out;

  char* p = (char*)d_ws;
  u16* xb  = (u16*)p;  p += (size_t)MROWS * D_ * 2;
  u16* wib = (u16*)p;  p += (size_t)D_ * D_ * 2;
  u16* wfb = (u16*)p;  p += (size_t)D_ * D_ * 2;
  u16* wob = (u16*)p;  p += (size_t)D_ * D_ * 2;
  float* ibuf = (float*)p; p += (size_t)MROWS * D_ * 4;
  float* fbuf = (float*)p; p += (size_t)MROWS * D_ * 4;
  float* ebuf = (float*)p; p += (size_t)MROWS * K_ * 4;
  float* sbuf = (float*)p; p += (size_t)MROWS * K_ * 4;
  float* Asc  = (float*)p; p += (size_t)B_ * NC_ * K_ * D_ * 4;
  float* Ssc  = (float*)p; p += (size_t)B_ * NC_ * K_ * D_ * 4;
  float* Psc  = (float*)p; p += (size_t)B_ * NC_ * D_ * 4;

  // -------- production path --------
  cast_kernel<<<MROWS * D_ / 1024, 256, 0, stream>>>(x, xb, MROWS * D_);
  cast_kernel<<<D_ * D_ / 1024, 256, 0, stream>>>(Wi, wib, D_ * D_);
  cast_kernel<<<D_ * D_ / 1024, 256, 0, stream>>>(Wf, wfb, D_ * D_);
  cast_kernel<<<D_ * D_ / 1024, 256, 0, stream>>>(Wo, wob, D_ * D_);

  ring_fused_prod<<<512, 512, 0, stream>>>(xb, wib, wfb, ibuf, fbuf);

  es_proj<<<MROWS / 4, 256, 0, stream>>>(x, We, Ws, ebuf, sbuf);

  scan_pass1<<<B_ * NC_ * 4, 256, 0, stream>>>(ibuf, fbuf, ebuf, Asc, Psc);
  scan_pass2<<<B_ * K_ * D_ / 256, 256, 0, stream>>>(Asc, Psc, Ssc);
  scan_pass3<<<B_ * NC_ * 4, 256, 0, stream>>>(ibuf, fbuf, ebuf, sbuf, Ssc);

  u16* ynb = xb;
  ln_kernel<<<MROWS / 4, 256, 0, stream>>>(ibuf, gamma, beta, ynb);

  gemm_bt_out<<<512, 256, 0, stream>>>(ynb, wob, out);

  // -------- ablations (write only to already-consumed ws buffers) --------
  // A4: exact o-proj clone, but target ws (fbuf) instead of d_out
  gemm_bt_ws<<<512, 256, 0, stream>>>(ynb, wob, fbuf);
  // A1: half-M ring, MFMA+barrier skeleton only (stale LDS after prologue)
  ring_abl_nostage<<<256, 512, 0, stream>>>(xb, wib, wfb, ibuf, fbuf);
  // A2: half-M ring, staging+vmcnt+barriers only (no ds_read/MFMA)
  ring_abl_nomfma<<<256, 512, 0, stream>>>(xb, wib, wfb, ibuf, fbuf);
}

// Round 8
// 275.065 us; speedup vs baseline: 1.3926x; 1.3926x over previous
//
#include <hip/hip_runtime.h>
#include <hip/hip_bf16.h>
#include <stdint.h>

#define B_ 4
#define N_ 2048
#define D_ 1024
#define K_ 16
#define MROWS (B_*N_)      // 8192
#define NC_ 32
#define CLEN_ (N_/NC_)     // 64

typedef unsigned short u16;
typedef __attribute__((ext_vector_type(8))) short bf16x8;
typedef __attribute__((ext_vector_type(8))) short short8;
typedef __attribute__((ext_vector_type(4))) float f32x4;

__device__ __forceinline__ u16 f2bf(float f) {
  uint32_t u = __float_as_uint(f);
  u = u + 0x7fffu + ((u >> 16) & 1u);
  return (u16)(u >> 16);
}
__device__ __forceinline__ float bf2f(u16 h) {
  uint32_t u = ((uint32_t)h) << 16;
  return __uint_as_float(u);
}
// fast f-gate: exp(logsigmoid(z)/16)
__device__ __forceinline__ float fgate(float z) {
  float ls = (z >= 0.0f) ? -__logf(1.0f + __expf(-z)) : (z - __logf(1.0f + __expf(z)));
  return __expf(ls * 0.0625f);
}

// ---------------- cast fp32 -> bf16 (vectorized) ----------------
__global__ __launch_bounds__(256) void cast_kernel(const float* __restrict__ in,
                                                   u16* __restrict__ out, int n) {
  int i = (blockIdx.x * 256 + threadIdx.x) * 4;
  if (i >= n) return;
  float4 v = *(const float4*)(in + i);
  ushort4 o;
  o.x = f2bf(v.x); o.y = f2bf(v.y); o.z = f2bf(v.z); o.w = f2bf(v.w);
  *(ushort4*)(out + i) = o;
}

#define GL_LDS(gp, lp) \
  __builtin_amdgcn_global_load_lds( \
      (const __attribute__((address_space(1))) void*)(gp), \
      (__attribute__((address_space(3))) void*)(lp), 16, 0, 0)

#define WAITVM(n)  asm volatile("s_waitcnt vmcnt(" #n ")" ::: "memory")
#define SCHEDB()   __builtin_amdgcn_sched_barrier(0)

// ---------------- counted-vmcnt ring GEMM (R4 structure; bf16 outputs) ----
__global__ __launch_bounds__(512, 1) void ring_fused(const u16* __restrict__ A,
                                                     const u16* __restrict__ W0,
                                                     const u16* __restrict__ W1,
                                                     u16* __restrict__ C0,
                                                     u16* __restrict__ C1) {
  __shared__ __align__(16) u16 lds[3 * 24576];   // 147456 B

  const int tid = threadIdx.x;
  const int w = tid >> 6, l = tid & 63;
  const int wr = w >> 1, wc = w & 1;

  const int orig = blockIdx.x;
  const int wg = (orig & 7) * 64 + (orig >> 3);   // nwg = 512
  const int bm = wg / 16;
  const int bn = wg % 16;

  const u16* W;
  u16* C;
  int ncol0;
  if (bn >= 8) { W = W1; C = C1; ncol0 = (bn - 8) * 128; }
  else         { W = W0; C = C0; ncol0 = bn * 128; }

  const int sw = ((l & 7) ^ ((l >> 3) & 7)) * 8;
  const u16* aSrc = A + (size_t)(bm * 256 + w * 8 + (l >> 3)) * 1024 + sw;
  const u16* bSrc = W + (size_t)(ncol0 + w * 8 + (l >> 3)) * 1024 + sw;

#define STAGE_T(t, slot) do { \
    const int _sb = (slot) * 49152 + w * 1024; \
    _Pragma("unroll") \
    for (int j = 0; j < 4; ++j) \
      GL_LDS(aSrc + (size_t)j * 65536 + (t) * 64, (char*)lds + _sb + j * 8192); \
    _Pragma("unroll") \
    for (int j = 0; j < 2; ++j) \
      GL_LDS(bSrc + (size_t)j * 65536 + (t) * 64, (char*)lds + _sb + 32768 + j * 8192); \
  } while (0)

  const int sxe = (l & 7) << 3;
  const int klo = (l >> 4) * 8;
  const int aR0 = (wr * 64 + (l & 15)) * 64;
  const int bR0 = (wc * 64 + (l & 15)) * 64 + 16384;

  f32x4 acc[4][4] = {};

#define COMPUTE(slot) do { \
    const u16* S = lds + (slot) * 24576; \
    bf16x8 b0[4], a0[4], b1[4], a1[4]; \
    _Pragma("unroll") \
    for (int n = 0; n < 4; ++n) b0[n] = *(const bf16x8*)&S[bR0 + n * 1024 + (klo ^ sxe)]; \
    _Pragma("unroll") \
    for (int m = 0; m < 4; ++m) a0[m] = *(const bf16x8*)&S[aR0 + m * 1024 + (klo ^ sxe)]; \
    _Pragma("unroll") \
    for (int n = 0; n < 4; ++n) b1[n] = *(const bf16x8*)&S[bR0 + n * 1024 + ((klo + 32) ^ sxe)]; \
    _Pragma("unroll") \
    for (int m = 0; m < 4; ++m) a1[m] = *(const bf16x8*)&S[aR0 + m * 1024 + ((klo + 32) ^ sxe)]; \
    asm volatile("s_waitcnt lgkmcnt(8)" ::: "memory"); \
    SCHEDB(); \
    __builtin_amdgcn_s_setprio(1); \
    _Pragma("unroll") \
    for (int m = 0; m < 4; ++m) \
      _Pragma("unroll") \
      for (int n = 0; n < 4; ++n) \
        acc[m][n] = __builtin_amdgcn_mfma_f32_16x16x32_bf16(a0[m], b0[n], acc[m][n], 0, 0, 0); \
    __builtin_amdgcn_s_setprio(0); \
    asm volatile("s_waitcnt lgkmcnt(0)" ::: "memory"); \
    SCHEDB(); \
    __builtin_amdgcn_s_setprio(1); \
    _Pragma("unroll") \
    for (int m = 0; m < 4; ++m) \
      _Pragma("unroll") \
      for (int n = 0; n < 4; ++n) \
        acc[m][n] = __builtin_amdgcn_mfma_f32_16x16x32_bf16(a1[m], b1[n], acc[m][n], 0, 0, 0); \
    __builtin_amdgcn_s_setprio(0); \
  } while (0)

  STAGE_T(0, 0);
  STAGE_T(1, 1);
  WAITVM(6);
  __builtin_amdgcn_s_barrier();
  SCHEDB();

#pragma unroll
  for (int t = 0; t < 16; ++t) {
    if (t + 2 < 16) STAGE_T(t + 2, (t + 2) % 3);
    COMPUTE(t % 3);
    if (t < 15) {
      if (t == 14) WAITVM(0);
      else         WAITVM(6);
      __builtin_amdgcn_s_barrier();
      SCHEDB();
    }
  }

  // epilogue: bf16 stores (no gate — gate moved into scan)
  const int orow0 = bm * 256 + wr * 64 + (l >> 4) * 4;
  const int ocol0 = ncol0 + wc * 64 + (l & 15);
#pragma unroll
  for (int m = 0; m < 4; ++m)
#pragma unroll
    for (int n = 0; n < 4; ++n)
#pragma unroll
      for (int r = 0; r < 4; ++r)
        C[(size_t)(orow0 + m * 16 + r) * 1024 + ocol0 + n * 16] = f2bf(acc[m][n][r]);
#undef STAGE_T
#undef COMPUTE
}

// ---------------- R1-exact simple GEMM (o-proj; best measured 103us) -------
__global__ __launch_bounds__(256) void gemm_bt(const u16* __restrict__ A,
                                               const u16* __restrict__ W,
                                               float* __restrict__ C,
                                               int M, int N, int Kk, int epi) {
  __shared__ u16 As[128 * 32];
  __shared__ u16 Bs[128 * 32];
  const int tid = threadIdx.x;
  const int w = tid >> 6, l = tid & 63;
  const int nbn = N >> 7;
  const int bm = blockIdx.x / nbn, bn = blockIdx.x % nbn;
  const int wm = (w >> 1) * 64, wn = (w & 1) * 64;
  const int lr = l & 15, lk = (l >> 4) * 8;

  f32x4 acc[4][4] = {};

  for (int kt = 0; kt < Kk; kt += 32) {
#pragma unroll
    for (int j = 0; j < 2; ++j) {
      int ofs = w * 1024 + j * 4096;
      int gofs = ofs + l * 16;
      int row = gofs >> 6;
      int ke = (gofs & 63) >> 1;
      const u16* ga = A + (size_t)(bm * 128 + row) * Kk + kt + ke;
      const u16* gb = W + (size_t)(bn * 128 + row) * Kk + kt + ke;
      GL_LDS(ga, (char*)As + ofs);
      GL_LDS(gb, (char*)Bs + ofs);
    }
    __syncthreads();
    bf16x8 af[4], bfr[4];
#pragma unroll
    for (int i2 = 0; i2 < 4; ++i2) {
      af[i2]  = *(const bf16x8*)&As[(wm + i2 * 16 + lr) * 32 + lk];
      bfr[i2] = *(const bf16x8*)&Bs[(wn + i2 * 16 + lr) * 32 + lk];
    }
#pragma unroll
    for (int i2 = 0; i2 < 4; ++i2)
#pragma unroll
      for (int j2 = 0; j2 < 4; ++j2)
        acc[i2][j2] = __builtin_amdgcn_mfma_f32_16x16x32_bf16(af[i2], bfr[j2], acc[i2][j2], 0, 0, 0);
    __syncthreads();
  }

  const int orow0 = bm * 128 + wm + (l >> 4) * 4;
  const int ocol0 = bn * 128 + wn + (l & 15);
#pragma unroll
  for (int i2 = 0; i2 < 4; ++i2)
#pragma unroll
    for (int j2 = 0; j2 < 4; ++j2)
#pragma unroll
      for (int r = 0; r < 4; ++r)
        C[(size_t)(orow0 + i2 * 16 + r) * N + ocol0 + j2 * 16] = acc[i2][j2][r];
}

// ---------------- e/s projections (fp32 x; unchanged) ----------------
__global__ __launch_bounds__(256) void es_proj(const float* __restrict__ x,
                                               const float* __restrict__ We,
                                               const float* __restrict__ Ws,
                                               float* __restrict__ e,
                                               float* __restrict__ s) {
  int row = blockIdx.x * 4 + (threadIdx.x >> 6);
  int l = threadIdx.x & 63;
  const float* xr = x + (size_t)row * D_;
  float4 xv[4];
#pragma unroll
  for (int j = 0; j < 4; ++j) xv[j] = *(const float4*)(xr + j * 256 + l * 4);
  float pe[K_], ps[K_];
#pragma unroll
  for (int k = 0; k < K_; ++k) {
    float ae = 0.f, as_ = 0.f;
#pragma unroll
    for (int j = 0; j < 4; ++j) {
      float4 wv = *(const float4*)(We + (size_t)k * D_ + j * 256 + l * 4);
      float4 sv = *(const float4*)(Ws + (size_t)k * D_ + j * 256 + l * 4);
      ae  += xv[j].x * wv.x + xv[j].y * wv.y + xv[j].z * wv.z + xv[j].w * wv.w;
      as_ += xv[j].x * sv.x + xv[j].y * sv.y + xv[j].z * sv.z + xv[j].w * sv.w;
    }
    pe[k] = ae; ps[k] = as_;
  }
#pragma unroll
  for (int k = 0; k < K_; ++k) {
    float ae = pe[k], as_ = ps[k];
    for (int off = 32; off > 0; off >>= 1) {
      ae  += __shfl_down(ae, off);
      as_ += __shfl_down(as_, off);
    }
    if (l == 0) {
      e[(size_t)row * K_ + k] = ae;
      s[(size_t)row * K_ + k] = as_;
    }
  }
}

// ---------------- scan pass1 (bf16 i/z inputs, gate recomputed) ------------
__global__ __launch_bounds__(256) void scan_pass1(const u16* __restrict__ ibb,
                                                  const u16* __restrict__ zbb,
                                                  const float* __restrict__ ebuf,
                                                  float* __restrict__ Asc,
                                                  float* __restrict__ Psc) {
  int bid = blockIdx.x;
  int dq = bid & 3, c = (bid >> 2) & (NC_ - 1), b = bid >> 7;
  int d = dq * 256 + threadIdx.x;
  int t0 = c * CLEN_;
  float m[K_];
#pragma unroll
  for (int k = 0; k < K_; ++k) m[k] = 0.f;
  float p = 1.0f;
  const u16* ip = ibb + ((size_t)b * N_ + t0) * D_ + d;
  const u16* zp = zbb + ((size_t)b * N_ + t0) * D_ + d;
  const float* ep = ebuf + ((size_t)b * N_ + t0) * K_;
  for (int t = 0; t < CLEN_; ++t) {
    float it = bf2f(ip[(size_t)t * D_]);
    float ft = fgate(bf2f(zp[(size_t)t * D_]));
    p *= ft;
#pragma unroll
    for (int k = 0; k < K_; ++k) m[k] = ft * m[k] + ep[t * K_ + k] * it;
  }
  float* ap = Asc + (((size_t)b * NC_ + c) * K_) * D_ + d;
#pragma unroll
  for (int k = 0; k < K_; ++k) ap[(size_t)k * D_] = m[k];
  Psc[((size_t)b * NC_ + c) * D_ + d] = p;
}

// ---------------- scan pass2 (unchanged) ----------------
__global__ __launch_bounds__(256) void scan_pass2(const float* __restrict__ Asc,
                                                  const float* __restrict__ Psc,
                                                  float* __restrict__ Ssc) {
  int idx = blockIdx.x * 256 + threadIdx.x;
  int d = idx & (D_ - 1);
  int k = (idx >> 10) & (K_ - 1);
  int b = idx >> 14;
  float M = 0.f;
  for (int c = 0; c < NC_; ++c) {
    size_t base = (((size_t)b * NC_ + c) * K_ + k) * D_ + d;
    float a = Asc[base];
    float pp = Psc[((size_t)b * NC_ + c) * D_ + d];
    Ssc[base] = M;
    M = pp * M + a;
  }
}

// ---------------- scan pass3 (bf16 in, bf16 y out) ----------------
__global__ __launch_bounds__(256) void scan_pass3(const u16* __restrict__ ibb,
                                                  const u16* __restrict__ zbb,
                                                  const float* __restrict__ ebuf,
                                                  const float* __restrict__ sbuf,
                                                  const float* __restrict__ Ssc,
                                                  u16* __restrict__ ybb) {
  int bid = blockIdx.x;
  int dq = bid & 3, c = (bid >> 2) & (NC_ - 1), b = bid >> 7;
  int d = dq * 256 + threadIdx.x;
  int t0 = c * CLEN_;
  float m[K_];
  const float* sp0 = Ssc + (((size_t)b * NC_ + c) * K_) * D_ + d;
#pragma unroll
  for (int k = 0; k < K_; ++k) m[k] = sp0[(size_t)k * D_];
  const u16* ip = ibb + ((size_t)b * N_ + t0) * D_ + d;
  const u16* zp = zbb + ((size_t)b * N_ + t0) * D_ + d;
  u16* yp = ybb + ((size_t)b * N_ + t0) * D_ + d;
  const float* ep = ebuf + ((size_t)b * N_ + t0) * K_;
  const float* wp = sbuf + ((size_t)b * N_ + t0) * K_;
  for (int t = 0; t < CLEN_; ++t) {
    float it = bf2f(ip[(size_t)t * D_]);
    float ft = fgate(bf2f(zp[(size_t)t * D_]));
    float y = 0.f;
#pragma unroll
    for (int k = 0; k < K_; ++k) {
      m[k] = ft * m[k] + ep[t * K_ + k] * it;
      y += wp[t * K_ + k] * m[k];
    }
    yp[(size_t)t * D_] = f2bf(y);
  }
}

// ---------------- LayerNorm (bf16 in) -> bf16 ----------------
__global__ __launch_bounds__(256) void ln_kernel(const u16* __restrict__ y,
                                                 const float* __restrict__ gamma,
                                                 const float* __restrict__ beta,
                                                 u16* __restrict__ yn) {
  int row = blockIdx.x * 4 + (threadIdx.x >> 6);
  int l = threadIdx.x & 63;
  const u16* yr = y + (size_t)row * D_;
  // lane l owns elems [l*16, l*16+16)
  float v[16];
  float sum = 0.f;
#pragma unroll
  for (int j = 0; j < 2; ++j) {
    short8 raw = *(const short8*)(yr + l * 16 + j * 8);
#pragma unroll
    for (int q = 0; q < 8; ++q) {
      float f = bf2f((u16)raw[q]);
      v[j * 8 + q] = f;
      sum += f;
    }
  }
  for (int off = 32; off > 0; off >>= 1) sum += __shfl_xor(sum, off);
  float mu = sum * (1.0f / D_);
  float vs = 0.f;
#pragma unroll
  for (int q = 0; q < 16; ++q) { float dx = v[q] - mu; vs += dx * dx; }
  for (int off = 32; off > 0; off >>= 1) vs += __shfl_xor(vs, off);
  float rstd = rsqrtf(vs * (1.0f / D_) + 1e-5f);
  int col0 = l * 16;
#pragma unroll
  for (int j = 0; j < 4; ++j) {
    float4 g = *(const float4*)(gamma + col0 + j * 4);
    float4 bt = *(const float4*)(beta + col0 + j * 4);
    ushort4 o;
    o.x = f2bf((v[j * 4 + 0] - mu) * rstd * g.x + bt.x);
    o.y = f2bf((v[j * 4 + 1] - mu) * rstd * g.y + bt.y);
    o.z = f2bf((v[j * 4 + 2] - mu) * rstd * g.z + bt.z);
    o.w = f2bf((v[j * 4 + 3] - mu) * rstd * g.w + bt.w);
    *(ushort4*)(yn + (size_t)row * D_ + col0 + j * 4) = o;
  }
}

extern "C" void kernel_launch(void* const* d_in, const int* in_sizes, int n_in,
                              void* d_out, int out_size, void* d_ws, size_t ws_size,
                              hipStream_t stream) {
  const float* x     = (const float*)d_in[0];
  const float* Wi    = (const float*)d_in[1];
  const float* We    = (const float*)d_in[2];
  const float* Wf    = (const float*)d_in[3];
  const float* Ws    = (const float*)d_in[4];
  const float* gamma = (const float*)d_in[5];
  const float* beta  = (const float*)d_in[6];
  const float* Wo    = (const float*)d_in[7];
  float* out = (float*)d_out;

  char* p = (char*)d_ws;
  u16* xb  = (u16*)p;  p += (size_t)MROWS * D_ * 2;       // 16 MB (reused as yn)
  u16* wib = (u16*)p;  p += (size_t)D_ * D_ * 2;          // 2 MB
  u16* wfb = (u16*)p;  p += (size_t)D_ * D_ * 2;          // 2 MB
  u16* wob = (u16*)p;  p += (size_t)D_ * D_ * 2;          // 2 MB
  u16* ibb = (u16*)p;  p += (size_t)MROWS * D_ * 2;       // 16 MB
  u16* zbb = (u16*)p;  p += (size_t)MROWS * D_ * 2;       // 16 MB
  u16* ybb = (u16*)p;  p += (size_t)MROWS * D_ * 2;       // 16 MB
  float* ebuf = (float*)p; p += (size_t)MROWS * K_ * 4;   // 512 KB
  float* sbuf = (float*)p; p += (size_t)MROWS * K_ * 4;   // 512 KB
  float* Asc  = (float*)p; p += (size_t)B_ * NC_ * K_ * D_ * 4;  // 8 MB
  float* Ssc  = (float*)p; p += (size_t)B_ * NC_ * K_ * D_ * 4;  // 8 MB
  float* Psc  = (float*)p; p += (size_t)B_ * NC_ * D_ * 4;       // 512 KB

  cast_kernel<<<MROWS * D_ / 1024, 256, 0, stream>>>(x, xb, MROWS * D_);
  cast_kernel<<<D_ * D_ / 1024, 256, 0, stream>>>(Wi, wib, D_ * D_);
  cast_kernel<<<D_ * D_ / 1024, 256, 0, stream>>>(Wf, wfb, D_ * D_);
  cast_kernel<<<D_ * D_ / 1024, 256, 0, stream>>>(Wo, wob, D_ * D_);

  // fused i+f projection -> bf16 i and bf16 z (pre-gate)
  ring_fused<<<512, 512, 0, stream>>>(xb, wib, wfb, ibb, zbb);

  es_proj<<<MROWS / 4, 256, 0, stream>>>(x, We, Ws, ebuf, sbuf);

  scan_pass1<<<B_ * NC_ * 4, 256, 0, stream>>>(ibb, zbb, ebuf, Asc, Psc);
  scan_pass2<<<B_ * K_ * D_ / 256, 256, 0, stream>>>(Asc, Psc, Ssc);
  scan_pass3<<<B_ * NC_ * 4, 256, 0, stream>>>(ibb, zbb, ebuf, sbuf, Ssc, ybb);

  u16* ynb = xb;   // x no longer needed
  ln_kernel<<<MROWS / 4, 256, 0, stream>>>(ybb, gamma, beta, ynb);

  // o-proj: R1-exact gemm_bt (best measured)
  gemm_bt<<<512, 256, 0, stream>>>(ynb, wob, out, MROWS, D_, D_, 0);
}

// Round 9
// 201.258 us; speedup vs baseline: 1.9033x; 1.3667x over previous
//
#include <hip/hip_runtime.h>
#include <hip/hip_bf16.h>
#include <stdint.h>

#define B_ 4
#define N_ 2048
#define D_ 1024
#define K_ 16
#define MROWS (B_*N_)      // 8192
#define NC_ 32
#define CLEN_ (N_/NC_)     // 64

typedef unsigned short u16;
typedef __attribute__((ext_vector_type(8))) short bf16x8;
typedef __attribute__((ext_vector_type(8))) short short8;
typedef __attribute__((ext_vector_type(4))) float f32x4;

__device__ __forceinline__ u16 f2bf(float f) {
  uint32_t u = __float_as_uint(f);
  u = u + 0x7fffu + ((u >> 16) & 1u);
  return (u16)(u >> 16);
}
__device__ __forceinline__ float bf2f(u16 h) {
  uint32_t u = ((uint32_t)h) << 16;
  return __uint_as_float(u);
}
// fast f-gate: exp(logsigmoid(z)/16)
__device__ __forceinline__ float fgate(float z) {
  float ls = (z >= 0.0f) ? -__logf(1.0f + __expf(-z)) : (z - __logf(1.0f + __expf(z)));
  return __expf(ls * 0.0625f);
}

// ---------------- cast fp32 -> bf16 (vectorized) ----------------
__global__ __launch_bounds__(256) void cast_kernel(const float* __restrict__ in,
                                                   u16* __restrict__ out, int n) {
  int i = (blockIdx.x * 256 + threadIdx.x) * 4;
  if (i >= n) return;
  float4 v = *(const float4*)(in + i);
  ushort4 o;
  o.x = f2bf(v.x); o.y = f2bf(v.y); o.z = f2bf(v.z); o.w = f2bf(v.w);
  *(ushort4*)(out + i) = o;
}

#define GL_LDS(gp, lp) \
  __builtin_amdgcn_global_load_lds( \
      (const __attribute__((address_space(1))) void*)(gp), \
      (__attribute__((address_space(3))) void*)(lp), 16, 0, 0)

#define WAITVM(n)  asm volatile("s_waitcnt vmcnt(" #n ")" ::: "memory")
#define SCHEDB()   __builtin_amdgcn_sched_barrier(0)

// ---------------- counted-vmcnt ring GEMM (R4 structure; bf16 outputs) ----
__global__ __launch_bounds__(512, 1) void ring_fused(const u16* __restrict__ A,
                                                     const u16* __restrict__ W0,
                                                     const u16* __restrict__ W1,
                                                     u16* __restrict__ C0,
                                                     u16* __restrict__ C1) {
  __shared__ __align__(16) u16 lds[3 * 24576];   // 147456 B

  const int tid = threadIdx.x;
  const int w = tid >> 6, l = tid & 63;
  const int wr = w >> 1, wc = w & 1;

  const int orig = blockIdx.x;
  const int wg = (orig & 7) * 64 + (orig >> 3);   // nwg = 512
  const int bm = wg / 16;
  const int bn = wg % 16;

  const u16* W;
  u16* C;
  int ncol0;
  if (bn >= 8) { W = W1; C = C1; ncol0 = (bn - 8) * 128; }
  else         { W = W0; C = C0; ncol0 = bn * 128; }

  const int sw = ((l & 7) ^ ((l >> 3) & 7)) * 8;
  const u16* aSrc = A + (size_t)(bm * 256 + w * 8 + (l >> 3)) * 1024 + sw;
  const u16* bSrc = W + (size_t)(ncol0 + w * 8 + (l >> 3)) * 1024 + sw;

#define STAGE_T(t, slot) do { \
    const int _sb = (slot) * 49152 + w * 1024; \
    _Pragma("unroll") \
    for (int j = 0; j < 4; ++j) \
      GL_LDS(aSrc + (size_t)j * 65536 + (t) * 64, (char*)lds + _sb + j * 8192); \
    _Pragma("unroll") \
    for (int j = 0; j < 2; ++j) \
      GL_LDS(bSrc + (size_t)j * 65536 + (t) * 64, (char*)lds + _sb + 32768 + j * 8192); \
  } while (0)

  const int sxe = (l & 7) << 3;
  const int klo = (l >> 4) * 8;
  const int aR0 = (wr * 64 + (l & 15)) * 64;
  const int bR0 = (wc * 64 + (l & 15)) * 64 + 16384;

  f32x4 acc[4][4] = {};

#define COMPUTE(slot) do { \
    const u16* S = lds + (slot) * 24576; \
    bf16x8 b0[4], a0[4], b1[4], a1[4]; \
    _Pragma("unroll") \
    for (int n = 0; n < 4; ++n) b0[n] = *(const bf16x8*)&S[bR0 + n * 1024 + (klo ^ sxe)]; \
    _Pragma("unroll") \
    for (int m = 0; m < 4; ++m) a0[m] = *(const bf16x8*)&S[aR0 + m * 1024 + (klo ^ sxe)]; \
    _Pragma("unroll") \
    for (int n = 0; n < 4; ++n) b1[n] = *(const bf16x8*)&S[bR0 + n * 1024 + ((klo + 32) ^ sxe)]; \
    _Pragma("unroll") \
    for (int m = 0; m < 4; ++m) a1[m] = *(const bf16x8*)&S[aR0 + m * 1024 + ((klo + 32) ^ sxe)]; \
    asm volatile("s_waitcnt lgkmcnt(8)" ::: "memory"); \
    SCHEDB(); \
    __builtin_amdgcn_s_setprio(1); \
    _Pragma("unroll") \
    for (int m = 0; m < 4; ++m) \
      _Pragma("unroll") \
      for (int n = 0; n < 4; ++n) \
        acc[m][n] = __builtin_amdgcn_mfma_f32_16x16x32_bf16(a0[m], b0[n], acc[m][n], 0, 0, 0); \
    __builtin_amdgcn_s_setprio(0); \
    asm volatile("s_waitcnt lgkmcnt(0)" ::: "memory"); \
    SCHEDB(); \
    __builtin_amdgcn_s_setprio(1); \
    _Pragma("unroll") \
    for (int m = 0; m < 4; ++m) \
      _Pragma("unroll") \
      for (int n = 0; n < 4; ++n) \
        acc[m][n] = __builtin_amdgcn_mfma_f32_16x16x32_bf16(a1[m], b1[n], acc[m][n], 0, 0, 0); \
    __builtin_amdgcn_s_setprio(0); \
  } while (0)

  STAGE_T(0, 0);
  STAGE_T(1, 1);
  WAITVM(6);
  __builtin_amdgcn_s_barrier();
  SCHEDB();

#pragma unroll
  for (int t = 0; t < 16; ++t) {
    if (t + 2 < 16) STAGE_T(t + 2, (t + 2) % 3);
    COMPUTE(t % 3);
    if (t < 15) {
      if (t == 14) WAITVM(0);
      else         WAITVM(6);
      __builtin_amdgcn_s_barrier();
      SCHEDB();
    }
  }

  // epilogue: bf16 stores (no gate — gate moved into scan)
  const int orow0 = bm * 256 + wr * 64 + (l >> 4) * 4;
  const int ocol0 = ncol0 + wc * 64 + (l & 15);
#pragma unroll
  for (int m = 0; m < 4; ++m)
#pragma unroll
    for (int n = 0; n < 4; ++n)
#pragma unroll
      for (int r = 0; r < 4; ++r)
        C[(size_t)(orow0 + m * 16 + r) * 1024 + ocol0 + n * 16] = f2bf(acc[m][n][r]);
#undef STAGE_T
#undef COMPUTE
}

// ---------------- R1-exact simple GEMM (o-proj; best measured) -------------
__global__ __launch_bounds__(256) void gemm_bt(const u16* __restrict__ A,
                                               const u16* __restrict__ W,
                                               float* __restrict__ C,
                                               int M, int N, int Kk, int epi) {
  __shared__ u16 As[128 * 32];
  __shared__ u16 Bs[128 * 32];
  const int tid = threadIdx.x;
  const int w = tid >> 6, l = tid & 63;
  const int nbn = N >> 7;
  const int bm = blockIdx.x / nbn, bn = blockIdx.x % nbn;
  const int wm = (w >> 1) * 64, wn = (w & 1) * 64;
  const int lr = l & 15, lk = (l >> 4) * 8;

  f32x4 acc[4][4] = {};

  for (int kt = 0; kt < Kk; kt += 32) {
#pragma unroll
    for (int j = 0; j < 2; ++j) {
      int ofs = w * 1024 + j * 4096;
      int gofs = ofs + l * 16;
      int row = gofs >> 6;
      int ke = (gofs & 63) >> 1;
      const u16* ga = A + (size_t)(bm * 128 + row) * Kk + kt + ke;
      const u16* gb = W + (size_t)(bn * 128 + row) * Kk + kt + ke;
      GL_LDS(ga, (char*)As + ofs);
      GL_LDS(gb, (char*)Bs + ofs);
    }
    __syncthreads();
    bf16x8 af[4], bfr[4];
#pragma unroll
    for (int i2 = 0; i2 < 4; ++i2) {
      af[i2]  = *(const bf16x8*)&As[(wm + i2 * 16 + lr) * 32 + lk];
      bfr[i2] = *(const bf16x8*)&Bs[(wn + i2 * 16 + lr) * 32 + lk];
    }
#pragma unroll
    for (int i2 = 0; i2 < 4; ++i2)
#pragma unroll
      for (int j2 = 0; j2 < 4; ++j2)
        acc[i2][j2] = __builtin_amdgcn_mfma_f32_16x16x32_bf16(af[i2], bfr[j2], acc[i2][j2], 0, 0, 0);
    __syncthreads();
  }

  const int orow0 = bm * 128 + wm + (l >> 4) * 4;
  const int ocol0 = bn * 128 + wn + (l & 15);
#pragma unroll
  for (int i2 = 0; i2 < 4; ++i2)
#pragma unroll
    for (int j2 = 0; j2 < 4; ++j2)
#pragma unroll
      for (int r = 0; r < 4; ++r)
        C[(size_t)(orow0 + i2 * 16 + r) * N + ocol0 + j2 * 16] = acc[i2][j2][r];
}

// ---------------- e/s via MFMA: [8192,1024] x [32,1024]^T ----------------
// Block: 64 rows, 256 thr (4 waves x 16 rows).  B = We(0-15)||Ws(16-31) cast
// to bf16 in LDS once (chunk-XOR swizzled).  A: bf16 xb, dbuf K128 tiles via
// global_load_lds with pre-swizzled source (rule 21).  8 K-tiles, 8 barriers.
__global__ __launch_bounds__(256) void es_mfma(const u16* __restrict__ xb,
                                               const float* __restrict__ We,
                                               const float* __restrict__ Ws,
                                               float* __restrict__ e,
                                               float* __restrict__ s) {
  __shared__ __align__(16) u16 Bsm[32 * 1024];     // 64 KB persistent
  __shared__ __align__(16) u16 Asl[2][64 * 128];   // 2 x 16 KB dbuf

  const int tid = threadIdx.x;
  const int w = tid >> 6, l = tid & 63;
  const int bm = blockIdx.x;                       // 0..127

  // ---- one-time B load: fp32 -> bf16, swizzled (chunk c -> c ^ (row&15)) ----
#pragma unroll
  for (int q = 0; q < 16; ++q) {
    int g = q * 256 + tid;            // chunk id 0..4095 (32 rows x 128 chunks)
    int n = g >> 7;                   // row 0..31
    int c = g & 127;                  // 8-elem chunk within row
    const float* src = (n < 16 ? We + (size_t)n * 1024 : Ws + (size_t)(n - 16) * 1024) + c * 8;
    float4 v0 = *(const float4*)(src);
    float4 v1 = *(const float4*)(src + 4);
    short8 o;
    o[0] = (short)f2bf(v0.x); o[1] = (short)f2bf(v0.y);
    o[2] = (short)f2bf(v0.z); o[3] = (short)f2bf(v0.w);
    o[4] = (short)f2bf(v1.x); o[5] = (short)f2bf(v1.y);
    o[6] = (short)f2bf(v1.z); o[7] = (short)f2bf(v1.w);
    *(short8*)&Bsm[(size_t)n * 1024 + (size_t)(c ^ (n & 15)) * 8] = o;
  }

  // ---- A staging addressing (pre-swizzled source chunk) ----
  const int arow_par = w * 4 + (l >> 4);            // row parity within 16-row group
  const int csrc = (l & 15) ^ arow_par;             // source chunk for this lane

#define ESTAGE(t, buf) do { \
    _Pragma("unroll") \
    for (int j = 0; j < 4; ++j) { \
      const u16* gp = xb + (size_t)(bm * 64 + j * 16 + arow_par) * 1024 + (t) * 128 + csrc * 8; \
      GL_LDS(gp, (char*)&Asl[(buf)][0] + j * 4096 + w * 1024); \
    } \
  } while (0)

  f32x4 acc[2] = {};

  ESTAGE(0, 0);
  __syncthreads();    // drains vm+lgkm: B ready, A tile 0 ready

#pragma unroll
  for (int t = 0; t < 8; ++t) {
    if (t) { WAITVM(0); __builtin_amdgcn_s_barrier(); }
    if (t + 1 < 8) ESTAGE(t + 1, (t + 1) & 1);
    const int buf = t & 1;
#pragma unroll
    for (int ks = 0; ks < 4; ++ks) {
      // A frag: row w*16 + (l&15), logical chunk ks*4 + (l>>4), phys = ^ (l&15)
      bf16x8 af = *(const bf16x8*)&Asl[buf][(size_t)(w * 16 + (l & 15)) * 128 +
                                           (size_t)(((ks * 4 + (l >> 4)) ^ (l & 15))) * 8];
      // B frags: rows fj*16 + (l&15); logical chunk t*16 + ks*4 + (l>>4), phys low4 ^ (l&15)
      bf16x8 b0 = *(const bf16x8*)&Bsm[(size_t)(0 + (l & 15)) * 1024 +
                                       (size_t)(((t * 16 + ks * 4 + (l >> 4)) ^ (l & 15))) * 8];
      bf16x8 b1 = *(const bf16x8*)&Bsm[(size_t)(16 + (l & 15)) * 1024 +
                                       (size_t)(((t * 16 + ks * 4 + (l >> 4)) ^ (l & 15))) * 8];
      acc[0] = __builtin_amdgcn_mfma_f32_16x16x32_bf16(af, b0, acc[0], 0, 0, 0);
      acc[1] = __builtin_amdgcn_mfma_f32_16x16x32_bf16(af, b1, acc[1], 0, 0, 0);
    }
  }

  const int orow = bm * 64 + w * 16 + (l >> 4) * 4;
  const int ocol = l & 15;
#pragma unroll
  for (int r = 0; r < 4; ++r) {
    e[(size_t)(orow + r) * K_ + ocol] = acc[0][r];
    s[(size_t)(orow + r) * K_ + ocol] = acc[1][r];
  }
#undef ESTAGE
}

// ---------------- scan pass1 (bf16 i/z inputs, gate recomputed) ------------
__global__ __launch_bounds__(256) void scan_pass1(const u16* __restrict__ ibb,
                                                  const u16* __restrict__ zbb,
                                                  const float* __restrict__ ebuf,
                                                  float* __restrict__ Asc,
                                                  float* __restrict__ Psc) {
  int bid = blockIdx.x;
  int dq = bid & 3, c = (bid >> 2) & (NC_ - 1), b = bid >> 7;
  int d = dq * 256 + threadIdx.x;
  int t0 = c * CLEN_;
  float m[K_];
#pragma unroll
  for (int k = 0; k < K_; ++k) m[k] = 0.f;
  float p = 1.0f;
  const u16* ip = ibb + ((size_t)b * N_ + t0) * D_ + d;
  const u16* zp = zbb + ((size_t)b * N_ + t0) * D_ + d;
  const float* ep = ebuf + ((size_t)b * N_ + t0) * K_;
  for (int t = 0; t < CLEN_; ++t) {
    float it = bf2f(ip[(size_t)t * D_]);
    float ft = fgate(bf2f(zp[(size_t)t * D_]));
    p *= ft;
#pragma unroll
    for (int k = 0; k < K_; ++k) m[k] = ft * m[k] + ep[t * K_ + k] * it;
  }
  float* ap = Asc + (((size_t)b * NC_ + c) * K_) * D_ + d;
#pragma unroll
  for (int k = 0; k < K_; ++k) ap[(size_t)k * D_] = m[k];
  Psc[((size_t)b * NC_ + c) * D_ + d] = p;
}

// ---------------- scan pass2 ----------------
__global__ __launch_bounds__(256) void scan_pass2(const float* __restrict__ Asc,
                                                  const float* __restrict__ Psc,
                                                  float* __restrict__ Ssc) {
  int idx = blockIdx.x * 256 + threadIdx.x;
  int d = idx & (D_ - 1);
  int k = (idx >> 10) & (K_ - 1);
  int b = idx >> 14;
  float M = 0.f;
  for (int c = 0; c < NC_; ++c) {
    size_t base = (((size_t)b * NC_ + c) * K_ + k) * D_ + d;
    float a = Asc[base];
    float pp = Psc[((size_t)b * NC_ + c) * D_ + d];
    Ssc[base] = M;
    M = pp * M + a;
  }
}

// ---------------- scan pass3 (bf16 in, bf16 y out) ----------------
__global__ __launch_bounds__(256) void scan_pass3(const u16* __restrict__ ibb,
                                                  const u16* __restrict__ zbb,
                                                  const float* __restrict__ ebuf,
                                                  const float* __restrict__ sbuf,
                                                  const float* __restrict__ Ssc,
                                                  u16* __restrict__ ybb) {
  int bid = blockIdx.x;
  int dq = bid & 3, c = (bid >> 2) & (NC_ - 1), b = bid >> 7;
  int d = dq * 256 + threadIdx.x;
  int t0 = c * CLEN_;
  float m[K_];
  const float* sp0 = Ssc + (((size_t)b * NC_ + c) * K_) * D_ + d;
#pragma unroll
  for (int k = 0; k < K_; ++k) m[k] = sp0[(size_t)k * D_];
  const u16* ip = ibb + ((size_t)b * N_ + t0) * D_ + d;
  const u16* zp = zbb + ((size_t)b * N_ + t0) * D_ + d;
  u16* yp = ybb + ((size_t)b * N_ + t0) * D_ + d;
  const float* ep = ebuf + ((size_t)b * N_ + t0) * K_;
  const float* wp = sbuf + ((size_t)b * N_ + t0) * K_;
  for (int t = 0; t < CLEN_; ++t) {
    float it = bf2f(ip[(size_t)t * D_]);
    float ft = fgate(bf2f(zp[(size_t)t * D_]));
    float y = 0.f;
#pragma unroll
    for (int k = 0; k < K_; ++k) {
      m[k] = ft * m[k] + ep[t * K_ + k] * it;
      y += wp[t * K_ + k] * m[k];
    }
    yp[(size_t)t * D_] = f2bf(y);
  }
}

// ---------------- LayerNorm (bf16 in) -> bf16 ----------------
__global__ __launch_bounds__(256) void ln_kernel(const u16* __restrict__ y,
                                                 const float* __restrict__ gamma,
                                                 const float* __restrict__ beta,
                                                 u16* __restrict__ yn) {
  int row = blockIdx.x * 4 + (threadIdx.x >> 6);
  int l = threadIdx.x & 63;
  const u16* yr = y + (size_t)row * D_;
  float v[16];
  float sum = 0.f;
#pragma unroll
  for (int j = 0; j < 2; ++j) {
    short8 raw = *(const short8*)(yr + l * 16 + j * 8);
#pragma unroll
    for (int q = 0; q < 8; ++q) {
      float f = bf2f((u16)raw[q]);
      v[j * 8 + q] = f;
      sum += f;
    }
  }
  for (int off = 32; off > 0; off >>= 1) sum += __shfl_xor(sum, off);
  float mu = sum * (1.0f / D_);
  float vs = 0.f;
#pragma unroll
  for (int q = 0; q < 16; ++q) { float dx = v[q] - mu; vs += dx * dx; }
  for (int off = 32; off > 0; off >>= 1) vs += __shfl_xor(vs, off);
  float rstd = rsqrtf(vs * (1.0f / D_) + 1e-5f);
  int col0 = l * 16;
#pragma unroll
  for (int j = 0; j < 4; ++j) {
    float4 g = *(const float4*)(gamma + col0 + j * 4);
    float4 bt = *(const float4*)(beta + col0 + j * 4);
    ushort4 o;
    o.x = f2bf((v[j * 4 + 0] - mu) * rstd * g.x + bt.x);
    o.y = f2bf((v[j * 4 + 1] - mu) * rstd * g.y + bt.y);
    o.z = f2bf((v[j * 4 + 2] - mu) * rstd * g.z + bt.z);
    o.w = f2bf((v[j * 4 + 3] - mu) * rstd * g.w + bt.w);
    *(ushort4*)(yn + (size_t)row * D_ + col0 + j * 4) = o;
  }
}

extern "C" void kernel_launch(void* const* d_in, const int* in_sizes, int n_in,
                              void* d_out, int out_size, void* d_ws, size_t ws_size,
                              hipStream_t stream) {
  const float* x     = (const float*)d_in[0];
  const float* Wi    = (const float*)d_in[1];
  const float* We    = (const float*)d_in[2];
  const float* Wf    = (const float*)d_in[3];
  const float* Ws    = (const float*)d_in[4];
  const float* gamma = (const float*)d_in[5];
  const float* beta  = (const float*)d_in[6];
  const float* Wo    = (const float*)d_in[7];
  float* out = (float*)d_out;

  char* p = (char*)d_ws;
  u16* xb  = (u16*)p;  p += (size_t)MROWS * D_ * 2;       // 16 MB (reused as yn)
  u16* wib = (u16*)p;  p += (size_t)D_ * D_ * 2;          // 2 MB
  u16* wfb = (u16*)p;  p += (size_t)D_ * D_ * 2;          // 2 MB
  u16* wob = (u16*)p;  p += (size_t)D_ * D_ * 2;          // 2 MB
  u16* ibb = (u16*)p;  p += (size_t)MROWS * D_ * 2;       // 16 MB
  u16* zbb = (u16*)p;  p += (size_t)MROWS * D_ * 2;       // 16 MB
  u16* ybb = (u16*)p;  p += (size_t)MROWS * D_ * 2;       // 16 MB
  float* ebuf = (float*)p; p += (size_t)MROWS * K_ * 4;   // 512 KB
  float* sbuf = (float*)p; p += (size_t)MROWS * K_ * 4;   // 512 KB
  float* Asc  = (float*)p; p += (size_t)B_ * NC_ * K_ * D_ * 4;  // 8 MB
  float* Ssc  = (float*)p; p += (size_t)B_ * NC_ * K_ * D_ * 4;  // 8 MB
  float* Psc  = (float*)p; p += (size_t)B_ * NC_ * D_ * 4;       // 512 KB

  cast_kernel<<<MROWS * D_ / 1024, 256, 0, stream>>>(x, xb, MROWS * D_);
  cast_kernel<<<D_ * D_ / 1024, 256, 0, stream>>>(Wi, wib, D_ * D_);
  cast_kernel<<<D_ * D_ / 1024, 256, 0, stream>>>(Wf, wfb, D_ * D_);
  cast_kernel<<<D_ * D_ / 1024, 256, 0, stream>>>(Wo, wob, D_ * D_);

  // fused i+f projection -> bf16 i and bf16 z (pre-gate)
  ring_fused<<<512, 512, 0, stream>>>(xb, wib, wfb, ibb, zbb);

  // e/s projections via MFMA (reads bf16 xb; weights cast in-kernel)
  es_mfma<<<MROWS / 64, 256, 0, stream>>>(xb, We, Ws, ebuf, sbuf);

  scan_pass1<<<B_ * NC_ * 4, 256, 0, stream>>>(ibb, zbb, ebuf, Asc, Psc);
  scan_pass2<<<B_ * K_ * D_ / 256, 256, 0, stream>>>(Asc, Psc, Ssc);
  scan_pass3<<<B_ * NC_ * 4, 256, 0, stream>>>(ibb, zbb, ebuf, sbuf, Ssc, ybb);

  u16* ynb = xb;   // x no longer needed
  ln_kernel<<<MROWS / 4, 256, 0, stream>>>(ybb, gamma, beta, ynb);

  // o-proj: R1-exact gemm_bt (best measured)
  gemm_bt<<<512, 256, 0, stream>>>(ynb, wob, out, MROWS, D_, D_, 0);
}